// Round 8
// baseline (16108.719 us; speedup 1.0000x reference)
//
#include <hip/hip_runtime.h>
#include <hip/hip_bf16.h>
#include <math.h>

// MultiLayerRNN on gfx950 — dataflow pipeline.
// ROOT CAUSE of rounds 0-7: inputs are FLOAT32 (per the reference), not bf16.
// Reading f32 as bf16 produced NaN-laden garbage; the epilogue clamp mapped
// NaN -> sigmoid(-30), giving the bit-exact repeated failure signature.
// This round: float inputs as const float*, converted to bf16 in-register at
// one-time fragment load; output written as float32. Ring transport keeps the
// round-7 atomic protocol (proven to complete); optimize once passing.

typedef __bf16 bf16_t;
typedef __bf16 bf16x8 __attribute__((ext_vector_type(8)));
typedef float  floatx4 __attribute__((ext_vector_type(4)));
typedef unsigned int  u32;
typedef unsigned short u16;
typedef u32 u32x4 __attribute__((ext_vector_type(4)));

#define S_LEN  1024
#define BATCH  64
#define EMBD   256
#define HID    512
#define VOCAB  50000
#define D0     8
#define D1     4
#define NGROUP 4
#define NSLICE 8
#define NFLAGS (2*NGROUP*S_LEN)
#define RING0_ELEMS ((size_t)D0*BATCH*HID)
#define RING1_ELEMS ((size_t)D1*BATCH*HID)
#define INIT_WORDS ((RING0_ELEMS + RING1_ELEMS)/2 + NFLAGS)

__device__ __attribute__((aligned(16))) bf16_t g_h0ring[RING0_ELEMS];
__device__ __attribute__((aligned(16))) bf16_t g_h1ring[RING1_ELEMS];
__device__ int g_flags[NFLAGS];

// ---- transport: scoped atomics, agent scope ----
__device__ __forceinline__ void at_store16(u16* p, u16 v) {
  __hip_atomic_store(p, v, __ATOMIC_RELAXED, __HIP_MEMORY_SCOPE_AGENT);
}
__device__ __forceinline__ void at_store32(u32* p, u32 v) {
  __hip_atomic_store(p, v, __ATOMIC_RELAXED, __HIP_MEMORY_SCOPE_AGENT);
}
__device__ __forceinline__ u32 at_load32(const u32* p) {
  return __hip_atomic_load(p, __ATOMIC_RELAXED, __HIP_MEMORY_SCOPE_AGENT);
}
__device__ __forceinline__ bf16x8 at_load_frag(const bf16_t* p) {
  const u32* q = (const u32*)p;
  u32x4 w;
  w[0] = at_load32(q + 0);
  w[1] = at_load32(q + 1);
  w[2] = at_load32(q + 2);
  w[3] = at_load32(q + 3);
  return __builtin_bit_cast(bf16x8, w);
}

__device__ __forceinline__ float act_tanh(float x) {
  x = fminf(fmaxf(x, -12.0f), 12.0f);   // NaN-proof: fmaxf(NaN,-12)=-12
  float e = __expf(2.0f * x);
  return 1.0f - 2.0f / (e + 1.0f);
}

// B-fragment from row-major f32 W[K][512]: elem j = (bf16)W[kbase+j][col]
__device__ __forceinline__ bf16x8 load_bfrag(const float* __restrict__ W,
                                             int kbase, int col) {
  bf16x8 v;
#pragma unroll
  for (int j = 0; j < 8; ++j) v[j] = (bf16_t)W[(size_t)(kbase + j) * HID + col];
  return v;
}
// A-fragment: 8 consecutive f32 -> bf16
__device__ __forceinline__ bf16x8 load_afrag(const float* __restrict__ p) {
  bf16x8 v;
#pragma unroll
  for (int j = 0; j < 8; ++j) v[j] = (bf16_t)p[j];
  return v;
}

__global__ __launch_bounds__(256) void k_init() {
  size_t i = (size_t)blockIdx.x * 256 + threadIdx.x;
  size_t r0w = RING0_ELEMS / 2, r1w = RING1_ELEMS / 2;
  if (i < r0w)             at_store32((u32*)g_h0ring + i, 0u);
  else if (i < r0w + r1w)  at_store32((u32*)g_h1ring + (i - r0w), 0u);
  else if (i < INIT_WORDS) at_store32((u32*)g_flags + (i - r0w - r1w), 0u);
}

__device__ __forceinline__ void poll_ge(const int* p, int target) {
  while (__hip_atomic_load(p, __ATOMIC_RELAXED, __HIP_MEMORY_SCOPE_AGENT) < target)
    __builtin_amdgcn_s_sleep(2);
}

__global__ __launch_bounds__(256, 1) void k_rnn(
    const int* __restrict__ x,
    const float* __restrict__ emb,
    const float* __restrict__ Wxh0,
    const float* __restrict__ bxh0, const float* __restrict__ bhh0,
    const float* __restrict__ Whh0,
    const float* __restrict__ Wxh1,
    const float* __restrict__ bxh1, const float* __restrict__ bhh1,
    const float* __restrict__ Whh1) {
  int* doneA = g_flags;
  int* doneC = g_flags + NGROUP * S_LEN;
  int bid = blockIdx.x;
  int role = bid & 1, g = (bid >> 1) & 3, s = bid >> 3;
  int tid = threadIdx.x;
  int wv = tid >> 6, lane = tid & 63, l15 = lane & 15, quad = lane >> 4;
  int col = s * 64 + wv * 16 + l15;  // output column (B-frag n / C-frag col)
  int arow = g * 16 + l15;           // batch row (A-frag m = lane&15)
  int crow = g * 16 + quad * 4;      // first C-frag row (row = quad*4 + reg)
  int kb = quad * 8;                 // A/B-frag k-base within a 32-chunk

  if (role == 0) {
    // ---- layer 0: h0[t] = tanh(emb[x_t]@Wxh0 + b + h0[t-1]@Whh0) ----
    bf16x8 bw[16], bwx[8];
#pragma unroll
    for (int ks = 0; ks < 16; ++ks) bw[ks]  = load_bfrag(Whh0, ks * 32 + kb, col);
#pragma unroll
    for (int ks = 0; ks < 8;  ++ks) bwx[ks] = load_bfrag(Wxh0, ks * 32 + kb, col);
    float bb = bxh0[col] + bhh0[col];

    int xrow = arow * S_LEN;
    bf16x8 ea[8], en[8];
    {
      int xi0 = x[xrow];
      xi0 = xi0 < 0 ? 0 : (xi0 >= VOCAB ? VOCAB - 1 : xi0);
      const float* ep = emb + (size_t)xi0 * EMBD + kb;
#pragma unroll
      for (int ks = 0; ks < 8; ++ks) ea[ks] = load_afrag(ep + ks * 32);
    }
    int xiB = x[xrow + 1];

    for (int t = 0; t < S_LEN; ++t) {
      if (t + 1 < S_LEN) {
        int xi = xiB < 0 ? 0 : (xiB >= VOCAB ? VOCAB - 1 : xiB);
        const float* ep = emb + (size_t)xi * EMBD + kb;
#pragma unroll
        for (int ks = 0; ks < 8; ++ks) en[ks] = load_afrag(ep + ks * 32);
      }
      int tn = (t + 2 < S_LEN) ? t + 2 : S_LEN - 1;
      int xiC = x[xrow + tn];

      // front GEMM (registers only) overlaps the poll wait
      floatx4 acc = (floatx4){bb, bb, bb, bb};
#pragma unroll
      for (int ks = 0; ks < 8; ++ks)
        acc = __builtin_amdgcn_mfma_f32_16x16x32_bf16(ea[ks], bwx[ks], acc, 0, 0, 0);

      if (tid == 0) {
        if (t > 0)   poll_ge(&doneA[g * S_LEN + t - 1], NSLICE);
        if (t >= D0) poll_ge(&doneC[g * S_LEN + t - D0], NSLICE);
      }
      __syncthreads();

      if (t > 0) {
        const bf16_t* hp = g_h0ring + (size_t)((t - 1) % D0) * BATCH * HID
                         + (size_t)arow * HID + kb;
#pragma unroll
        for (int ks = 0; ks < 16; ++ks) {
          bf16x8 af = at_load_frag(hp + ks * 32);
          acc = __builtin_amdgcn_mfma_f32_16x16x32_bf16(af, bw[ks], acc, 0, 0, 0);
        }
      }
      bf16_t* hw = g_h0ring + (size_t)(t % D0) * BATCH * HID
                 + (size_t)crow * HID + col;
#pragma unroll
      for (int i = 0; i < 4; ++i) {
        bf16_t hv = (bf16_t)act_tanh(acc[i]);
        at_store16((u16*)(hw + i * HID), __builtin_bit_cast(u16, hv));
      }

      __syncthreads(); // drains all waves' atomic stores (vmcnt) pre-release
      if (tid == 0)
        __hip_atomic_fetch_add(&doneA[g * S_LEN + t], 1, __ATOMIC_RELEASE,
                               __HIP_MEMORY_SCOPE_AGENT);
#pragma unroll
      for (int ks = 0; ks < 8; ++ks) ea[ks] = en[ks];
      xiB = xiC;
    }
  } else {
    // ---- layer 1: h1[t] = tanh(h0[t]@Wxh1 + b + h1[t-1]@Whh1) ----
    bf16x8 bwx[16], bwh[16];
#pragma unroll
    for (int ks = 0; ks < 16; ++ks) {
      bwx[ks] = load_bfrag(Wxh1, ks * 32 + kb, col);
      bwh[ks] = load_bfrag(Whh1, ks * 32 + kb, col);
    }
    float bb = bxh1[col] + bhh1[col];

    for (int t = 0; t < S_LEN; ++t) {
      if (tid == 0) {
        poll_ge(&doneA[g * S_LEN + t], NSLICE);
        if (t > 0) poll_ge(&doneC[g * S_LEN + t - 1], NSLICE);
      }
      __syncthreads();

      floatx4 acc = (floatx4){bb, bb, bb, bb};
      {
        const bf16_t* hp = g_h0ring + (size_t)(t % D0) * BATCH * HID
                         + (size_t)arow * HID + kb;
#pragma unroll
        for (int ks = 0; ks < 16; ++ks) {
          bf16x8 af = at_load_frag(hp + ks * 32);
          acc = __builtin_amdgcn_mfma_f32_16x16x32_bf16(af, bwx[ks], acc, 0, 0, 0);
        }
      }
      if (t > 0) {
        const bf16_t* hp = g_h1ring + (size_t)((t - 1) % D1) * BATCH * HID
                         + (size_t)arow * HID + kb;
#pragma unroll
        for (int ks = 0; ks < 16; ++ks) {
          bf16x8 af = at_load_frag(hp + ks * 32);
          acc = __builtin_amdgcn_mfma_f32_16x16x32_bf16(af, bwh[ks], acc, 0, 0, 0);
        }
      }
      bf16_t* hw = g_h1ring + (size_t)(t % D1) * BATCH * HID
                 + (size_t)crow * HID + col;
#pragma unroll
      for (int i = 0; i < 4; ++i) {
        bf16_t hv = (bf16_t)act_tanh(acc[i]);
        at_store16((u16*)(hw + i * HID), __builtin_bit_cast(u16, hv));
      }

      __syncthreads();
      if (tid == 0)
        __hip_atomic_fetch_add(&doneC[g * S_LEN + t], 1, __ATOMIC_RELEASE,
                               __HIP_MEMORY_SCOPE_AGENT);
    }
  }
}

__global__ __launch_bounds__(64) void k_out(const float* __restrict__ fc_w,
                                            const float* __restrict__ fc_b,
                                            float* __restrict__ out) {
  int b = threadIdx.x;
  const bf16_t* hr = g_h1ring + (size_t)((S_LEN - 1) % D1) * BATCH * HID
                   + (size_t)b * HID;
  float acc = fc_b[0];
#pragma unroll 4
  for (int k = 0; k < HID; k += 2) {
    u32 w = at_load32((const u32*)(hr + k));
    bf16_t h0 = __builtin_bit_cast(bf16_t, (u16)(w & 0xffffu));
    bf16_t h1 = __builtin_bit_cast(bf16_t, (u16)(w >> 16));
    acc += (float)h0 * fc_w[k] + (float)h1 * fc_w[k + 1];
  }
  acc = fminf(fmaxf(acc, -30.0f), 30.0f);  // NaN canary: NaN -> sigmoid(-30)
  out[b] = 1.0f / (1.0f + __expf(-acc));
}

extern "C" void kernel_launch(void* const* d_in, const int* in_sizes, int n_in,
                              void* d_out, int out_size, void* d_ws, size_t ws_size,
                              hipStream_t stream) {
  const int*   x    = (const int*)d_in[0];
  const float* emb  = (const float*)d_in[1];
  const float* Wxh0 = (const float*)d_in[2];
  const float* bxh0 = (const float*)d_in[3];
  const float* Whh0 = (const float*)d_in[4];
  const float* bhh0 = (const float*)d_in[5];
  const float* Wxh1 = (const float*)d_in[6];
  const float* bxh1 = (const float*)d_in[7];
  const float* Whh1 = (const float*)d_in[8];
  const float* bhh1 = (const float*)d_in[9];
  const float* fc_w = (const float*)d_in[10];
  const float* fc_b = (const float*)d_in[11];
  (void)d_ws; (void)ws_size; (void)in_sizes; (void)n_in; (void)out_size;

  hipLaunchKernelGGL(k_init, dim3((INIT_WORDS + 255) / 256), dim3(256), 0, stream);
  hipLaunchKernelGGL(k_rnn, dim3(NGROUP * 2 * NSLICE), dim3(256), 0, stream,
                     x, emb, Wxh0, bxh0, bhh0, Whh0, Wxh1, bxh1, bhh1, Whh1);
  hipLaunchKernelGGL(k_out, dim3(1), dim3(64), 0, stream,
                     fc_w, fc_b, (float*)d_out);
}